// Round 1
// baseline (266.331 us; speedup 1.0000x reference)
//
#include <hip/hip_runtime.h>
#include <hip/hip_bf16.h>
#include <stdint.h>

// Problem dims
#define T_TOK 2048
#define HD    1024
#define NE    8
#define FD    1408
#define F2D   2816

// GEMM tiling
#define BM 128
#define BN 64
#define BK 64
#define MAXSLOTS 5120   // 4096 live slots + 8*128 alignment padding

typedef __attribute__((ext_vector_type(8))) short bf16x8;
typedef __attribute__((ext_vector_type(4))) float f32x4;

__device__ __forceinline__ unsigned short f2bf(float f) {
  unsigned int u = __float_as_uint(f);
  u += 0x7FFFu + ((u >> 16) & 1u);   // RNE
  return (unsigned short)(u >> 16);
}

#define GLL16(gp, lp) __builtin_amdgcn_global_load_lds( \
    (const __attribute__((address_space(1))) void*)(gp), \
    (__attribute__((address_space(3))) void*)(lp), 16, 0, 0)

// ---------------------------------------------------------------------------
// Router: one wave per token. Computes f32 logits (matches ref selection),
// softmax over 8, top-2 (strict > keeps lowest index on ties, like top_k),
// atomic per-expert counts. Also converts x to bf16.
// ---------------------------------------------------------------------------
__global__ __launch_bounds__(256) void k_router(
    const float* __restrict__ x, const float* __restrict__ rw,
    unsigned short* __restrict__ xbf, int* __restrict__ ctrl,
    int* __restrict__ tok_e, float* __restrict__ tok_p)
{
  const int lane = threadIdx.x & 63;
  const int t = blockIdx.x * 4 + (threadIdx.x >> 6);
  const float* xr = x + (size_t)t * HD;

  float part[8];
#pragma unroll
  for (int e = 0; e < 8; ++e) part[e] = 0.f;

#pragma unroll
  for (int i = 0; i < 16; ++i) {
    const int h = i * 64 + lane;
    const float xv = xr[h];
    xbf[(size_t)t * HD + h] = f2bf(xv);
    const float4* rwr = reinterpret_cast<const float4*>(rw + (size_t)h * 8);
    float4 a = rwr[0], b = rwr[1];
    part[0] += xv * a.x; part[1] += xv * a.y; part[2] += xv * a.z; part[3] += xv * a.w;
    part[4] += xv * b.x; part[5] += xv * b.y; part[6] += xv * b.z; part[7] += xv * b.w;
  }
#pragma unroll
  for (int e = 0; e < 8; ++e) {
    float v = part[e];
#pragma unroll
    for (int d = 32; d; d >>= 1) v += __shfl_xor(v, d, 64);
    part[e] = v;
  }
  // softmax over 8 (all lanes redundantly)
  float m = part[0];
#pragma unroll
  for (int e = 1; e < 8; ++e) m = fmaxf(m, part[e]);
  float p[8], s = 0.f;
#pragma unroll
  for (int e = 0; e < 8; ++e) { p[e] = __expf(part[e] - m); s += p[e]; }
  const float inv = 1.f / s;
#pragma unroll
  for (int e = 0; e < 8; ++e) p[e] *= inv;

  int e0 = 0; float p0 = p[0];
#pragma unroll
  for (int e = 1; e < 8; ++e) if (p[e] > p0) { p0 = p[e]; e0 = e; }
  int e1 = -1; float p1 = -1.f;
#pragma unroll
  for (int e = 0; e < 8; ++e) if (e != e0 && p[e] > p1) { p1 = p[e]; e1 = e; }

  if (lane == 0) {
    tok_e[t * 2 + 0] = e0; tok_e[t * 2 + 1] = e1;
    tok_p[t * 2 + 0] = p0; tok_p[t * 2 + 1] = p1;
    atomicAdd(&ctrl[e0], 1);
    atomicAdd(&ctrl[e1], 1);
  }
}

// ---------------------------------------------------------------------------
// Offsets: BM-aligned exclusive scan of counts; fill padding slots with
// tok=0, p=0 (so they contribute exactly zero downstream).
// ---------------------------------------------------------------------------
__global__ __launch_bounds__(256) void k_offsets(
    int* __restrict__ ctrl, int* __restrict__ stok, float* __restrict__ sp)
{
  __shared__ int soff[8];
  if (threadIdx.x == 0) {
    int o = 0;
    for (int e = 0; e < 8; ++e) {
      ctrl[16 + e] = o; soff[e] = o;
      const int n = ctrl[e];
      o += (n + BM - 1) / BM * BM;
    }
  }
  __syncthreads();
  for (int e = 0; e < 8; ++e) {
    const int n = ctrl[e], o = soff[e];
    const int padEnd = (n + BM - 1) / BM * BM;
    for (int j = n + (int)threadIdx.x; j < padEnd; j += 256) {
      stok[o + j] = 0; sp[o + j] = 0.f;
    }
  }
}

// ---------------------------------------------------------------------------
// Scatter tokens into per-expert compacted slot lists.
// ---------------------------------------------------------------------------
__global__ __launch_bounds__(256) void k_scatter(
    int* __restrict__ ctrl, const int* __restrict__ tok_e,
    const float* __restrict__ tok_p, int* __restrict__ stok,
    float* __restrict__ sp)
{
  const int t = blockIdx.x * 256 + threadIdx.x;
#pragma unroll
  for (int k = 0; k < 2; ++k) {
    const int e = tok_e[t * 2 + k];
    const float pp = tok_p[t * 2 + k];
    const int pos = atomicAdd(&ctrl[8 + e], 1);  // cursor
    const int slot = ctrl[16 + e] + pos;
    stok[slot] = t; sp[slot] = pp;
  }
}

// ---------------------------------------------------------------------------
// Tiled transpose + f32->bf16 convert: src [z][R][C] f32 -> dst [z][C][R] bf16
// ---------------------------------------------------------------------------
__global__ __launch_bounds__(256) void k_transpose_cvt(
    const float* __restrict__ src, unsigned short* __restrict__ dst,
    int R, int C)
{
  const size_t zoff = (size_t)blockIdx.z * R * C;
  src += zoff; dst += zoff;
  const int r0 = blockIdx.y * 64, c0 = blockIdx.x * 64;
  __shared__ float tile[64][65];
  const int tr = threadIdx.x >> 4;         // 0..15
  const int tc = (threadIdx.x & 15) * 4;   // 0..60
#pragma unroll
  for (int p = 0; p < 4; ++p) {
    const int r = p * 16 + tr;
    float4 v = *reinterpret_cast<const float4*>(&src[(size_t)(r0 + r) * C + c0 + tc]);
    tile[r][tc + 0] = v.x; tile[r][tc + 1] = v.y;
    tile[r][tc + 2] = v.z; tile[r][tc + 3] = v.w;
  }
  __syncthreads();
#pragma unroll
  for (int p = 0; p < 4; ++p) {
    const int c = p * 16 + tr;   // source col = dest row
    ushort4 o;
    o.x = f2bf(tile[tc + 0][c]);
    o.y = f2bf(tile[tc + 1][c]);
    o.z = f2bf(tile[tc + 2][c]);
    o.w = f2bf(tile[tc + 3][c]);
    *reinterpret_cast<ushort4*>(&dst[(size_t)(c0 + c) * R + r0 + tc]) = o;
  }
}

// ---------------------------------------------------------------------------
// fc1: grouped GEMM  y = X[slots] @ w1[e]  (both SwiGLU halves), fused
// epilogue g = silu(y1)*y2*p -> bf16.  A gathered via per-lane global addr.
// ---------------------------------------------------------------------------
__global__ __launch_bounds__(256) void k_fc1(
    const unsigned short* __restrict__ xbf,   // [T][H] bf16
    const unsigned short* __restrict__ w1t,   // [E][2F][H] bf16
    const int* __restrict__ ctrl,
    const int* __restrict__ stok,
    const float* __restrict__ sp,
    unsigned short* __restrict__ g)           // [MAXSLOTS][F] bf16
{
  const int e  = blockIdx.z;
  const int mt = blockIdx.y;
  const int nt = blockIdx.x;
  const int cnt = ctrl[e];
  if (mt * BM >= cnt) return;
  const int rowbase = ctrl[16 + e] + mt * BM;
  const int n0 = nt * BN;

  __shared__ unsigned short sA[BM * BK];
  __shared__ unsigned short sB1[BN * BK];
  __shared__ unsigned short sB2[BN * BK];

  const int tid = threadIdx.x;
  const int lane = tid & 63;
  const int wave = tid >> 6;
  const int wm = wave >> 1, wn = wave & 1;

  const unsigned short* aSrc[4];
#pragma unroll
  for (int t4 = 0; t4 < 4; ++t4) {
    const int ci = (t4 * 4 + wave) * 64 + lane;
    const int row = ci >> 3, c16 = ci & 7;
    const int tok = stok[rowbase + row];
    aSrc[t4] = xbf + (size_t)tok * HD + c16 * 8;
  }
  const unsigned short* bSrc[4];   // [0..1]=gate half, [2..3]=up half
#pragma unroll
  for (int t4 = 0; t4 < 2; ++t4) {
    const int ci = (t4 * 4 + wave) * 64 + lane;
    const int row = ci >> 3, c16 = ci & 7;
    bSrc[t4]     = w1t + ((size_t)e * F2D + n0 + row) * HD + c16 * 8;
    bSrc[t4 + 2] = w1t + ((size_t)e * F2D + FD + n0 + row) * HD + c16 * 8;
  }

  const f32x4 zero = {0.f, 0.f, 0.f, 0.f};
  f32x4 acc1[4][2], acc2[4][2];
#pragma unroll
  for (int m = 0; m < 4; ++m)
#pragma unroll
    for (int n = 0; n < 2; ++n) { acc1[m][n] = zero; acc2[m][n] = zero; }

  for (int k0 = 0; k0 < HD; k0 += BK) {
#pragma unroll
    for (int t4 = 0; t4 < 4; ++t4)
      GLL16(aSrc[t4] + k0, sA + (t4 * 4 + wave) * 512);
#pragma unroll
    for (int t4 = 0; t4 < 2; ++t4) {
      GLL16(bSrc[t4] + k0,     sB1 + (t4 * 4 + wave) * 512);
      GLL16(bSrc[t4 + 2] + k0, sB2 + (t4 * 4 + wave) * 512);
    }
    __syncthreads();
#pragma unroll
    for (int kk = 0; kk < 2; ++kk) {
      const int krow = kk * 32 + (lane >> 4) * 8;
      bf16x8 af[4], b1f[2], b2f[2];
#pragma unroll
      for (int m = 0; m < 4; ++m)
        af[m] = *(const bf16x8*)&sA[(wm * 64 + m * 16 + (lane & 15)) * BK + krow];
#pragma unroll
      for (int n = 0; n < 2; ++n) {
        b1f[n] = *(const bf16x8*)&sB1[(wn * 32 + n * 16 + (lane & 15)) * BK + krow];
        b2f[n] = *(const bf16x8*)&sB2[(wn * 32 + n * 16 + (lane & 15)) * BK + krow];
      }
#pragma unroll
      for (int m = 0; m < 4; ++m)
#pragma unroll
        for (int n = 0; n < 2; ++n) {
          acc1[m][n] = __builtin_amdgcn_mfma_f32_16x16x32_bf16(af[m], b1f[n], acc1[m][n], 0, 0, 0);
          acc2[m][n] = __builtin_amdgcn_mfma_f32_16x16x32_bf16(af[m], b2f[n], acc2[m][n], 0, 0, 0);
        }
    }
    __syncthreads();
  }

  float prv[4][4];
#pragma unroll
  for (int m = 0; m < 4; ++m)
#pragma unroll
    for (int r = 0; r < 4; ++r)
      prv[m][r] = sp[rowbase + wm * 64 + m * 16 + (lane >> 4) * 4 + r];

#pragma unroll
  for (int m = 0; m < 4; ++m) {
    const int rb = rowbase + wm * 64 + m * 16 + (lane >> 4) * 4;
#pragma unroll
    for (int n = 0; n < 2; ++n) {
      const int col = n0 + wn * 32 + n * 16 + (lane & 15);
#pragma unroll
      for (int r = 0; r < 4; ++r) {
        const float y1 = acc1[m][n][r];
        const float y2 = acc2[m][n][r];
        const float gv = y1 / (1.f + __expf(-y1)) * y2 * prv[m][r];
        g[(size_t)(rb + r) * FD + col] = f2bf(gv);
      }
    }
  }
}

// ---------------------------------------------------------------------------
// fc2: grouped GEMM  o = g[slots] @ w2[e], epilogue atomicAdd into out
// (prob already folded into g; padding rows are exactly zero).
// ---------------------------------------------------------------------------
__global__ __launch_bounds__(256) void k_fc2(
    const unsigned short* __restrict__ g,     // [MAXSLOTS][F] bf16
    const unsigned short* __restrict__ w2t,   // [E][H][F] bf16
    const int* __restrict__ ctrl,
    const int* __restrict__ stok,
    float* __restrict__ out)                  // [T][H] f32, pre-zeroed
{
  const int e  = blockIdx.z;
  const int mt = blockIdx.y;
  const int nt = blockIdx.x;
  const int cnt = ctrl[e];
  if (mt * BM >= cnt) return;
  const int rowbase = ctrl[16 + e] + mt * BM;
  const int n0 = nt * BN;

  __shared__ unsigned short sA[BM * BK];
  __shared__ unsigned short sB[BN * BK];

  const int tid = threadIdx.x;
  const int lane = tid & 63;
  const int wave = tid >> 6;
  const int wm = wave >> 1, wn = wave & 1;

  const unsigned short* aSrc[4];
#pragma unroll
  for (int t4 = 0; t4 < 4; ++t4) {
    const int ci = (t4 * 4 + wave) * 64 + lane;
    const int row = ci >> 3, c16 = ci & 7;
    aSrc[t4] = g + (size_t)(rowbase + row) * FD + c16 * 8;
  }
  const unsigned short* bSrc[2];
#pragma unroll
  for (int t4 = 0; t4 < 2; ++t4) {
    const int ci = (t4 * 4 + wave) * 64 + lane;
    const int row = ci >> 3, c16 = ci & 7;
    bSrc[t4] = w2t + ((size_t)e * HD + n0 + row) * FD + c16 * 8;
  }

  const f32x4 zero = {0.f, 0.f, 0.f, 0.f};
  f32x4 acc[4][2];
#pragma unroll
  for (int m = 0; m < 4; ++m)
#pragma unroll
    for (int n = 0; n < 2; ++n) acc[m][n] = zero;

  for (int k0 = 0; k0 < FD; k0 += BK) {
#pragma unroll
    for (int t4 = 0; t4 < 4; ++t4)
      GLL16(aSrc[t4] + k0, sA + (t4 * 4 + wave) * 512);
#pragma unroll
    for (int t4 = 0; t4 < 2; ++t4)
      GLL16(bSrc[t4] + k0, sB + (t4 * 4 + wave) * 512);
    __syncthreads();
#pragma unroll
    for (int kk = 0; kk < 2; ++kk) {
      const int krow = kk * 32 + (lane >> 4) * 8;
      bf16x8 af[4], bf[2];
#pragma unroll
      for (int m = 0; m < 4; ++m)
        af[m] = *(const bf16x8*)&sA[(wm * 64 + m * 16 + (lane & 15)) * BK + krow];
#pragma unroll
      for (int n = 0; n < 2; ++n)
        bf[n] = *(const bf16x8*)&sB[(wn * 32 + n * 16 + (lane & 15)) * BK + krow];
#pragma unroll
      for (int m = 0; m < 4; ++m)
#pragma unroll
        for (int n = 0; n < 2; ++n)
          acc[m][n] = __builtin_amdgcn_mfma_f32_16x16x32_bf16(af[m], bf[n], acc[m][n], 0, 0, 0);
    }
    __syncthreads();
  }

  int tokv[4][4];
#pragma unroll
  for (int m = 0; m < 4; ++m)
#pragma unroll
    for (int r = 0; r < 4; ++r)
      tokv[m][r] = stok[rowbase + wm * 64 + m * 16 + (lane >> 4) * 4 + r];

#pragma unroll
  for (int m = 0; m < 4; ++m)
#pragma unroll
    for (int n = 0; n < 2; ++n) {
      const int col = n0 + wn * 32 + n * 16 + (lane & 15);
#pragma unroll
      for (int r = 0; r < 4; ++r)
        atomicAdd(&out[(size_t)tokv[m][r] * HD + col], acc[m][n][r]);
    }
}

// ---------------------------------------------------------------------------
extern "C" void kernel_launch(void* const* d_in, const int* in_sizes, int n_in,
                              void* d_out, int out_size, void* d_ws, size_t ws_size,
                              hipStream_t stream)
{
  const float* x  = (const float*)d_in[0];   // [2048,1,1024]
  const float* rw = (const float*)d_in[1];   // [1024,8]
  const float* w1 = (const float*)d_in[2];   // [8,1024,2816]
  const float* w2 = (const float*)d_in[3];   // [8,1408,1024]
  float* out = (float*)d_out;
  char* ws = (char*)d_ws;

  // ws layout (bytes)
  int*   ctrl  = (int*)(ws + 0);                         // cnt[8], cursor[8], off[8]
  int*   tok_e = (int*)(ws + 256);
  float* tok_p = (float*)(ws + 16640);
  int*   stok  = (int*)(ws + 33024);
  float* sp    = (float*)(ws + 53504);
  unsigned short* xbf = (unsigned short*)(ws + 73984);        // [T][H]
  unsigned short* w1t = (unsigned short*)(ws + 4268288);      // [E][2F][H]
  unsigned short* w2t = (unsigned short*)(ws + 50405632);     // [E][H][F]
  unsigned short* g   = (unsigned short*)(ws + 73474304);     // [MAXSLOTS][F]

  hipMemsetAsync(ws, 0, 256, stream);
  hipMemsetAsync(d_out, 0, (size_t)T_TOK * HD * sizeof(float), stream);

  k_router<<<T_TOK / 4, 256, 0, stream>>>(x, rw, xbf, ctrl, tok_e, tok_p);
  k_transpose_cvt<<<dim3(F2D / 64, HD / 64, NE), 256, 0, stream>>>(w1, w1t, HD, F2D);
  k_transpose_cvt<<<dim3(HD / 64, FD / 64, NE), 256, 0, stream>>>(w2, w2t, FD, HD);
  k_offsets<<<1, 256, 0, stream>>>(ctrl, stok, sp);
  k_scatter<<<T_TOK / 256, 256, 0, stream>>>(ctrl, tok_e, tok_p, stok, sp);
  k_fc1<<<dim3(FD / BN, T_TOK / BM, NE), 256, 0, stream>>>(xbf, w1t, ctrl, stok, sp, g);
  k_fc2<<<dim3(HD / BN, T_TOK / BM, NE), 256, 0, stream>>>(g, w2t, ctrl, stok, out);
}